// Round 1
// baseline (116.298 us; speedup 1.0000x reference)
//
#include <hip/hip_runtime.h>
#include <math.h>

// Problem constants (fixed by reference setup_inputs):
// features: (2, 256, 64, 64) f32 ; w_comp: (64,256,1,1) ; b_comp: (64,) ; w_enc: (100,64,3,3)
// out: (2, 256, 128, 128) f32
#define NB   2
#define CIN  256
#define CCMP 64
#define HH   64
#define WWD  64

// ws layout (floats):
//  wT    [256][64]                @ 0       (16384)
//  wencT [4][64][3][3][32]        @ 16384   (73728)   (tap-padded 25->32)
//  comp  [2][64][64][64]          @ 90112   (524288)
//  wgt   [2][64][4][25][64]       @ 614400  (819200)
// total 1,433,600 floats = 5.47 MB

__global__ __launch_bounds__(256) void transpose_wcomp(const float* __restrict__ w_comp,
                                                       float* __restrict__ wT) {
    int i = blockIdx.x * 256 + threadIdx.x;   // 16384 total
    if (i < CIN * CCMP) {
        int c = i >> 6, cc = i & 63;
        wT[c * 64 + cc] = w_comp[cc * CIN + c];
    }
}

__global__ __launch_bounds__(256) void transpose_wenc(const float* __restrict__ w_enc,
                                                      float* __restrict__ wencT) {
    int i = blockIdx.x * 256 + threadIdx.x;   // 73728 total
    if (i < 4 * 64 * 9 * 32) {
        int tap = i & 31;
        int r = i >> 5;                 // r = ((sub*64+cc)*3+dh)*3+dw
        int dw = r % 3;
        int dh = (r / 3) % 3;
        int cc = (r / 9) % 64;
        int sub = r / 576;
        float v = 0.f;
        if (tap < 25) {
            int o = tap * 4 + sub;      // pixel-shuffle: kp channel = tap*4 + (dy*2+dx)
            v = w_enc[((o * 64 + cc) * 3 + dh) * 3 + dw];
        }
        wencT[i] = v;
    }
}

// compress: comp[n][cc][h][w] = b[cc] + sum_c feat[n][c][h][w] * w_comp[cc][c]
// grid 512 x 256 threads; thread = (pixel p, 4 consecutive cc)
__global__ __launch_bounds__(256) void compress_kernel(const float* __restrict__ feat,
                                                       const float* __restrict__ wT,
                                                       const float* __restrict__ b_comp,
                                                       float* __restrict__ comp) {
    int gid = blockIdx.x * 256 + threadIdx.x;   // 131072
    int p   = gid & 8191;                       // n*4096 + hw
    int ccg = gid >> 13;                        // 0..15
    int n   = p >> 12;
    int hw  = p & 4095;
    int cc0 = ccg * 4;
    const float* f = feat + (size_t)n * CIN * 4096 + hw;
    float a0 = b_comp[cc0 + 0], a1 = b_comp[cc0 + 1];
    float a2 = b_comp[cc0 + 2], a3 = b_comp[cc0 + 3];
    #pragma unroll 4
    for (int c = 0; c < CIN; ++c) {
        float fv = f[(size_t)c * 4096];
        float4 wv = *reinterpret_cast<const float4*>(wT + c * 64 + cc0); // wave-uniform
        a0 += fv * wv.x; a1 += fv * wv.y; a2 += fv * wv.z; a3 += fv * wv.w;
    }
    float* o = comp + (size_t)n * CCMP * 4096 + hw;
    o[(size_t)(cc0 + 0) * 4096] = a0;
    o[(size_t)(cc0 + 1) * 4096] = a1;
    o[(size_t)(cc0 + 2) * 4096] = a2;
    o[(size_t)(cc0 + 3) * 4096] = a3;
}

// enc 3x3 conv + softmax over 25 taps, fused.
// block = (n, h, sub); 512 blocks x 512 threads (8 cc-quarters x 64 w)
__global__ __launch_bounds__(512) void enc_softmax_kernel(const float* __restrict__ comp,
                                                          const float* __restrict__ wencT,
                                                          float* __restrict__ wgt) {
    int b = blockIdx.x;              // ((n*64+h)*4 + sub)
    int sub = b & 3;
    int h   = (b >> 2) & 63;
    int n   = b >> 8;
    int tid = threadIdx.x;
    int w   = tid & 63;
    int ccq = tid >> 6;              // 0..7

    __shared__ float part[8][25][66];   // 52.8 KB
    __shared__ float fin[25][66];       //  6.6 KB

    float acc[25];
    #pragma unroll
    for (int t = 0; t < 25; ++t) acc[t] = 0.f;

    const float* wsub = wencT + sub * 18432;
    for (int cq = 0; cq < 8; ++cq) {
        int cc = ccq * 8 + cq;
        const float* crow = comp + (((size_t)n * 64 + cc) << 12);
        const float* wcc  = wsub + cc * 288;
        #pragma unroll
        for (int dh = 0; dh < 3; ++dh) {
            int hh = h + dh - 1;
            bool rowok = (unsigned)hh < 64u;
            float fv[3];
            #pragma unroll
            for (int dw = 0; dw < 3; ++dw) {
                int ww = w + dw - 1;
                fv[dw] = (rowok && (unsigned)ww < 64u) ? crow[(hh << 6) + ww] : 0.f;
            }
            #pragma unroll
            for (int dw = 0; dw < 3; ++dw) {
                const float* wp = wcc + dh * 96 + dw * 32;
                float f = fv[dw];
                const float4* w4 = reinterpret_cast<const float4*>(wp);
                #pragma unroll
                for (int k = 0; k < 6; ++k) {
                    float4 q = w4[k];
                    acc[4 * k + 0] += f * q.x;
                    acc[4 * k + 1] += f * q.y;
                    acc[4 * k + 2] += f * q.z;
                    acc[4 * k + 3] += f * q.w;
                }
                acc[24] += f * wp[24];
            }
        }
    }

    #pragma unroll
    for (int t = 0; t < 25; ++t) part[ccq][t][w] = acc[t];
    __syncthreads();

    for (int idx = tid; idx < 25 * 64; idx += 512) {
        int t = idx >> 6, ww = idx & 63;
        float s = 0.f;
        #pragma unroll
        for (int q = 0; q < 8; ++q) s += part[q][t][ww];
        fin[t][ww] = s;
    }
    __syncthreads();

    if (tid < 64) {
        float m = -1e30f;
        #pragma unroll
        for (int t = 0; t < 25; ++t) m = fmaxf(m, fin[t][tid]);
        float ev[25];
        float s = 0.f;
        #pragma unroll
        for (int t = 0; t < 25; ++t) { ev[t] = expf(fin[t][tid] - m); s += ev[t]; }
        float inv = 1.f / s;
        float* o = wgt + (size_t)b * 1600;     // [n][h][sub][25][64]
        #pragma unroll
        for (int t = 0; t < 25; ++t) o[t * 64 + tid] = ev[t] * inv;
    }
}

// apply: out[n][c][2h+dy][2w+dx] = sum_{i,j} feat[n][c][h+i-2][w+j-2] * wgt[n][h][dy*2+dx][i*5+j][w]
// grid 1024 = (n,h) x 8 cgroups(32c); block 256 = 64 w x 4 ci; thread handles 8 channels, 4 subpixels
__global__ __launch_bounds__(256) void apply_kernel(const float* __restrict__ feat,
                                                    const float* __restrict__ wgt,
                                                    float* __restrict__ out) {
    int b = blockIdx.x;
    int cg = b & 7;
    int h  = (b >> 3) & 63;
    int n  = b >> 9;
    int tid = threadIdx.x;
    int w  = tid & 63;
    int ci = tid >> 6;
    int c0 = cg * 32 + ci * 8;
    const float* fbase = feat + ((size_t)(n * CIN + c0)) * 4096;
    const float* wg = wgt + ((size_t)((n * 64 + h) * 4)) * 1600; // [sub][25][64]

    float acc[4][8];
    #pragma unroll
    for (int s = 0; s < 4; ++s)
        #pragma unroll
        for (int k = 0; k < 8; ++k) acc[s][k] = 0.f;

    #pragma unroll
    for (int i = 0; i < 5; ++i) {
        int hh = h + i - 2;
        if ((unsigned)hh >= 64u) continue;        // block-uniform branch
        #pragma unroll
        for (int j = 0; j < 5; ++j) {
            int ww = w + j - 2;
            bool ok = (unsigned)ww < 64u;
            int t = i * 5 + j;
            float wv[4];
            #pragma unroll
            for (int s = 0; s < 4; ++s) wv[s] = wg[(s * 25 + t) * 64 + w];
            #pragma unroll
            for (int k = 0; k < 8; ++k) {
                float fv = ok ? fbase[(size_t)k * 4096 + (hh << 6) + ww] : 0.f;
                #pragma unroll
                for (int s = 0; s < 4; ++s) acc[s][k] += fv * wv[s];
            }
        }
    }

    #pragma unroll
    for (int k = 0; k < 8; ++k) {
        float* o = out + ((size_t)(n * CIN + c0 + k) * 128 + 2 * h) * 128 + 2 * w;
        float2 lo = make_float2(acc[0][k], acc[1][k]);
        float2 hi = make_float2(acc[2][k], acc[3][k]);
        *reinterpret_cast<float2*>(o) = lo;
        *reinterpret_cast<float2*>(o + 128) = hi;
    }
}

extern "C" void kernel_launch(void* const* d_in, const int* in_sizes, int n_in,
                              void* d_out, int out_size, void* d_ws, size_t ws_size,
                              hipStream_t stream) {
    const float* features = (const float*)d_in[0];
    const float* w_comp   = (const float*)d_in[1];
    const float* b_comp   = (const float*)d_in[2];
    const float* w_enc    = (const float*)d_in[3];
    float* out = (float*)d_out;
    float* ws  = (float*)d_ws;

    float* wT    = ws;              // 16384
    float* wencT = ws + 16384;      // 73728
    float* comp  = ws + 90112;      // 524288
    float* wgt   = ws + 614400;     // 819200

    hipLaunchKernelGGL(transpose_wcomp, dim3(64),  dim3(256), 0, stream, w_comp, wT);
    hipLaunchKernelGGL(transpose_wenc,  dim3(288), dim3(256), 0, stream, w_enc, wencT);
    hipLaunchKernelGGL(compress_kernel, dim3(512), dim3(256), 0, stream, features, wT, b_comp, comp);
    hipLaunchKernelGGL(enc_softmax_kernel, dim3(512), dim3(512), 0, stream, comp, wencT, wgt);
    hipLaunchKernelGGL(apply_kernel, dim3(1024), dim3(256), 0, stream, features, wgt, out);
}

// Round 2
// 74.884 us; speedup vs baseline: 1.5530x; 1.5530x over previous
//
#include <hip/hip_runtime.h>
#include <hip/hip_bf16.h>
#include <math.h>

// CARAFE on MI355X.
// features: (2,256,64,64) f32 ; w_comp: (64,256) ; b_comp: (64,) ; w_enc: (100,64,3,3)
// out: (2,256,128,128) f32
#define NB   2
#define CIN  256
#define CCMP 64

typedef __attribute__((ext_vector_type(8))) short short8v;  // 8 bf16 (4 VGPRs)
typedef __attribute__((ext_vector_type(4))) float f32x4;    // MFMA accum

// ws layout (float units):
//  wT    [256][64]                         @ 0        (16384)
//  compB [8192 pix][64 cc] bf16            @ 16384    (262144 fl)
//  Bsw   [18 ks][8 nf][64 lane][8] bf16    @ 278528   (36864 fl)
//  wgt   [2][64 h][4 sub][25 tap][64 w]    @ 315392   (819200 fl)
// total 1,134,592 floats = 4.33 MB

__device__ inline ushort f2bf(float x) {
    __hip_bfloat16 b = __float2bfloat16(x);
    return *reinterpret_cast<ushort*>(&b);
}

__global__ __launch_bounds__(256) void transpose_wcomp(const float* __restrict__ w_comp,
                                                       float* __restrict__ wT) {
    int i = blockIdx.x * 256 + threadIdx.x;   // 16384 total
    if (i < CIN * CCMP) {
        int c = i >> 6, cc = i & 63;
        wT[c * 64 + cc] = w_comp[cc * CIN + c];
    }
}

// Build MFMA B-fragments for the enc conv GEMM.
// k = convtap*64 + cc  (convtap = dh*3+dw, 9 taps; K = 576 = 18 ksteps of 32)
// o = outtap*4 + sub   (enc output channel, 100 real, padded to 128)
// Bsw[((ks*8 + nf)*64 + lane)*8 + j] = bf16( B[k0 + (lane>>4)*8 + j][nf*16 + (lane&15)] )
__global__ __launch_bounds__(256) void prep_bsw(const float* __restrict__ w_enc,
                                                ushort* __restrict__ Bsw) {
    int i = blockIdx.x * 256 + threadIdx.x;   // 73728 total
    if (i >= 18 * 8 * 64 * 8) return;
    int j    = i & 7;
    int lane = (i >> 3) & 63;
    int rest = i >> 9;
    int nf   = rest & 7;
    int ks   = rest >> 3;
    int ct   = ks >> 1;                  // conv tap 0..8
    int dh   = ct / 3, dw = ct % 3;
    int cc   = (ks & 1) * 32 + (lane >> 4) * 8 + j;
    int o    = nf * 16 + (lane & 15);
    float v  = 0.f;
    if (o < 100) v = w_enc[((o * 64 + cc) * 3 + dh) * 3 + dw];
    Bsw[i] = f2bf(v);
}

// compress: compB[p][cc] = bf16( b[cc] + sum_c feat[n][c][hw] * wT[c][cc] )
// thread = (pixel p = gid>>4, ccg = gid&15 -> 4 cc each); wave covers 4 pixels x 16 ccg.
__global__ __launch_bounds__(256) void compress_v2(const float* __restrict__ feat,
                                                   const float* __restrict__ wT,
                                                   const float* __restrict__ b_comp,
                                                   ushort* __restrict__ compB) {
    int gid = blockIdx.x * 256 + threadIdx.x;   // 131072
    int p   = gid >> 4;
    int cc0 = (gid & 15) * 4;
    int n   = p >> 12;
    int hw  = p & 4095;
    const float* f = feat + (size_t)n * CIN * 4096 + hw;
    float4 bv = *reinterpret_cast<const float4*>(b_comp + cc0);
    float a0 = bv.x, a1 = bv.y, a2 = bv.z, a3 = bv.w;
    #pragma unroll 4
    for (int c = 0; c < CIN; ++c) {
        float fv = f[(size_t)c * 4096];
        float4 wv = *reinterpret_cast<const float4*>(wT + c * 64 + cc0);
        a0 += fv * wv.x; a1 += fv * wv.y; a2 += fv * wv.z; a3 += fv * wv.w;
    }
    ushort4 o;
    o.x = f2bf(a0); o.y = f2bf(a1); o.z = f2bf(a2); o.w = f2bf(a3);
    *reinterpret_cast<ushort4*>(compB + (size_t)p * 64 + cc0) = o;
}

// enc conv as MFMA GEMM (M=32 pixels per block, N=128 padded, K=576) + fused softmax.
// Block = 32 consecutive pixels of one (n,h) row. 4 waves: (m = M-frag, nh = N-half).
__global__ __launch_bounds__(256) void enc_gemm_softmax(const ushort* __restrict__ compB,
                                                        const ushort* __restrict__ Bsw,
                                                        float* __restrict__ wgt) {
    int tile = blockIdx.x;          // 256 tiles
    int p0 = tile * 32;
    int n = p0 >> 12, h = (p0 >> 6) & 63, w0 = p0 & 63;   // w0 in {0,32}
    int tid = threadIdx.x, lane = tid & 63, wid = tid >> 6;
    int m = wid & 1, nh = wid >> 1;
    int nf0 = nh * 4;
    int lr = lane & 15, lk = lane >> 4;
    int wpix = w0 + m * 16 + lr;     // this lane's pixel w-coordinate (A row)

    f32x4 acc[4] = {f32x4{0,0,0,0}, f32x4{0,0,0,0}, f32x4{0,0,0,0}, f32x4{0,0,0,0}};

    #pragma unroll
    for (int ks = 0; ks < 18; ++ks) {
        int ct = ks >> 1;
        int dh = ct / 3, dw = ct % 3;
        int hh = h + dh - 1;
        if ((unsigned)hh >= 64u) continue;        // block-uniform (A row = 0)
        int ww = wpix + dw - 1;
        short8v a = {};
        if ((unsigned)ww < 64u) {
            const ushort* ap = compB + ((size_t)(n * 4096 + hh * 64 + ww) * 64
                                        + (ks & 1) * 32 + lk * 8);
            a = *reinterpret_cast<const short8v*>(ap);
        }
        const ushort* bp = Bsw + ((size_t)(ks * 8 + nf0) * 64 + lane) * 8;
        #pragma unroll
        for (int q = 0; q < 4; ++q) {
            short8v b = *reinterpret_cast<const short8v*>(bp + q * 512);
            acc[q] = __builtin_amdgcn_mfma_f32_16x16x32_bf16(a, b, acc[q], 0, 0, 0);
        }
    }

    // Epilogue: kp tile -> LDS, softmax over 25 taps per (pixel, sub), write wgt.
    __shared__ float kp_lds[32][132];
    #pragma unroll
    for (int q = 0; q < 4; ++q) {
        int col = (nf0 + q) * 16 + lr;
        #pragma unroll
        for (int i = 0; i < 4; ++i)
            kp_lds[m * 16 + lk * 4 + i][col] = acc[q][i];
    }
    __syncthreads();

    if (tid < 128) {
        int pl = tid & 31, sub = tid >> 5;
        float v[25];
        float mx = -1e30f;
        #pragma unroll
        for (int t = 0; t < 25; ++t) {
            v[t] = kp_lds[pl][t * 4 + sub];
            mx = fmaxf(mx, v[t]);
        }
        float s = 0.f;
        #pragma unroll
        for (int t = 0; t < 25; ++t) { v[t] = expf(v[t] - mx); s += v[t]; }
        float inv = 1.f / s;
        float* o = wgt + ((size_t)((n * 64 + h) * 4 + sub)) * 1600 + (w0 + pl);
        #pragma unroll
        for (int t = 0; t < 25; ++t) o[t * 64] = v[t] * inv;
    }
}

// apply: out[n][c][2h+dy][2w+dx] = sum_{i,j} feat[n][c][h+i-2][w+j-2] * wgt[n][h][dy*2+dx][i*5+j][w]
__global__ __launch_bounds__(256) void apply_kernel(const float* __restrict__ feat,
                                                    const float* __restrict__ wgt,
                                                    float* __restrict__ out) {
    int b = blockIdx.x;
    int cg = b & 7;
    int h  = (b >> 3) & 63;
    int n  = b >> 9;
    int tid = threadIdx.x;
    int w  = tid & 63;
    int ci = tid >> 6;
    int c0 = cg * 32 + ci * 8;
    const float* fbase = feat + ((size_t)(n * CIN + c0)) * 4096;
    const float* wg = wgt + ((size_t)((n * 64 + h) * 4)) * 1600; // [sub][25][64]

    float acc[4][8];
    #pragma unroll
    for (int s = 0; s < 4; ++s)
        #pragma unroll
        for (int k = 0; k < 8; ++k) acc[s][k] = 0.f;

    #pragma unroll
    for (int i = 0; i < 5; ++i) {
        int hh = h + i - 2;
        if ((unsigned)hh >= 64u) continue;        // block-uniform branch
        #pragma unroll
        for (int j = 0; j < 5; ++j) {
            int ww = w + j - 2;
            bool ok = (unsigned)ww < 64u;
            int t = i * 5 + j;
            float wv[4];
            #pragma unroll
            for (int s = 0; s < 4; ++s) wv[s] = wg[(s * 25 + t) * 64 + w];
            #pragma unroll
            for (int k = 0; k < 8; ++k) {
                float fv = ok ? fbase[(size_t)k * 4096 + (hh << 6) + ww] : 0.f;
                #pragma unroll
                for (int s = 0; s < 4; ++s) acc[s][k] += fv * wv[s];
            }
        }
    }

    #pragma unroll
    for (int k = 0; k < 8; ++k) {
        float* o = out + ((size_t)(n * CIN + c0 + k) * 128 + 2 * h) * 128 + 2 * w;
        *reinterpret_cast<float2*>(o) = make_float2(acc[0][k], acc[1][k]);
        *reinterpret_cast<float2*>(o + 128) = make_float2(acc[2][k], acc[3][k]);
    }
}

extern "C" void kernel_launch(void* const* d_in, const int* in_sizes, int n_in,
                              void* d_out, int out_size, void* d_ws, size_t ws_size,
                              hipStream_t stream) {
    const float* features = (const float*)d_in[0];
    const float* w_comp   = (const float*)d_in[1];
    const float* b_comp   = (const float*)d_in[2];
    const float* w_enc    = (const float*)d_in[3];
    float* out = (float*)d_out;
    float* ws  = (float*)d_ws;

    float*  wT    = ws;                              // 16384 fl
    ushort* compB = (ushort*)(ws + 16384);           // 524288 bf16
    ushort* Bsw   = (ushort*)(ws + 278528);          // 73728 bf16
    float*  wgt   = ws + 315392;                     // 819200 fl

    hipLaunchKernelGGL(transpose_wcomp, dim3(64),  dim3(256), 0, stream, w_comp, wT);
    hipLaunchKernelGGL(prep_bsw,        dim3(288), dim3(256), 0, stream, w_enc, Bsw);
    hipLaunchKernelGGL(compress_v2,     dim3(512), dim3(256), 0, stream, features, wT, b_comp, compB);
    hipLaunchKernelGGL(enc_gemm_softmax, dim3(256), dim3(256), 0, stream, compB, Bsw, wgt);
    hipLaunchKernelGGL(apply_kernel,    dim3(1024), dim3(256), 0, stream, features, wgt, out);
}

// Round 3
// 56.148 us; speedup vs baseline: 2.0713x; 1.3337x over previous
//
#include <hip/hip_runtime.h>
#include <hip/hip_bf16.h>
#include <math.h>

// CARAFE on MI355X (gfx950).
// features: (2,256,64,64) f32 ; w_comp: (64,256) ; b_comp: (64,) ; w_enc: (100,64,3,3)
// out: (2,256,128,128) f32
#define CIN 256

typedef __attribute__((ext_vector_type(8))) short short8v;  // 8 bf16 (4 VGPRs)
typedef __attribute__((ext_vector_type(4))) float f32x4;    // MFMA accum

// ws layout (float units):
//  Bsw   [18ks][8nf][64lane][8] bf16   @ 0         (36864 fl)
//  Bc    [8ks][4nf][64lane][8] bf16    @ 36864     (8192 fl)
//  featT [8192 p][256 c] bf16          @ 45056     (1048576 fl)
//  wgt   [2][64h][4sub][25tap][64w] f32 @ 45056    (819200 fl)  -- ALIASES featT (dead by then)
//  compB [8192 p][64 cc] bf16          @ 1093632   (262144 fl)
// total 1,355,776 fl = 5.42 MB

__device__ inline ushort f2bf(float x) {
    __hip_bfloat16 b = __float2bfloat16(x);
    return *reinterpret_cast<ushort*>(&b);
}

// Pre-swizzle both weight tensors into MFMA B-fragment layout.
// enc GEMM: k = convtap*64 + cc (K=576, 18 ksteps), o = outtap*4 + sub (N=100 pad 128)
// compress GEMM: k = c (K=256, 8 ksteps), col = cc (N=64)
__global__ __launch_bounds__(256) void prep_weights(const float* __restrict__ w_comp,
                                                    const float* __restrict__ w_enc,
                                                    ushort* __restrict__ Bsw,
                                                    ushort* __restrict__ Bc) {
    int bid = blockIdx.x, tid = threadIdx.x;
    if (bid < 288) {
        int i = bid * 256 + tid;                 // 73728
        int j = i & 7, lane = (i >> 3) & 63, rest = i >> 9;
        int nf = rest & 7, ks = rest >> 3;       // ks 0..17
        int ct = ks >> 1, dh = ct / 3, dw = ct % 3;
        int cc = (ks & 1) * 32 + (lane >> 4) * 8 + j;
        int o  = nf * 16 + (lane & 15);
        float v = (o < 100) ? w_enc[((o * 64 + cc) * 3 + dh) * 3 + dw] : 0.f;
        Bsw[i] = f2bf(v);
    } else {
        int i = (bid - 288) * 256 + tid;         // 16384
        int j = i & 7, lane = (i >> 3) & 63, rest = i >> 9;
        int nf = rest & 3, ks = rest >> 2;       // ks 0..7
        int c  = ks * 32 + (lane >> 4) * 8 + j;
        int cc = nf * 16 + (lane & 15);
        Bc[i] = f2bf(w_comp[cc * 256 + c]);
    }
}

// NCHW f32 -> [pixel][c] bf16 via 64x64 LDS tile (coalesced load and store).
__global__ __launch_bounds__(256) void feat_transpose(const float* __restrict__ feat,
                                                      ushort* __restrict__ featT) {
    __shared__ float lds[64][65];
    int bid = blockIdx.x;                 // 512 = 128 p-tiles x 4 c-tiles
    int ct = bid & 3, pt = bid >> 2;
    int c0 = ct * 64, p0 = pt * 64;
    int n = p0 >> 12, hw0 = p0 & 4095;
    int tid = threadIdx.x;
    int pl = tid & 63, cr = tid >> 6;
    const float* src = feat + ((size_t)(n * CIN + c0 + cr)) * 4096 + hw0 + pl;
    #pragma unroll
    for (int rr = 0; rr < 16; ++rr)
        lds[rr * 4 + cr][pl] = src[(size_t)rr * 4 * 4096];
    __syncthreads();
    int cp = tid & 31, pr = tid >> 5;
    uint* dst = (uint*)featT;
    #pragma unroll
    for (int rr = 0; rr < 8; ++rr) {
        int pp = rr * 8 + pr;
        uint u = (uint)f2bf(lds[cp * 2][pp]) | ((uint)f2bf(lds[cp * 2 + 1][pp]) << 16);
        dst[(((size_t)(p0 + pp) * 256 + c0) >> 1) + cp] = u;
    }
}

// compress as MFMA GEMM: comp[p][cc] = bias[cc] + sum_c featT[p][c] * w_comp[cc][c]
// M=16/block (512 blocks), 4 waves = 4 N-frags, K=256 (8 ksteps).
__global__ __launch_bounds__(256) void compress_gemm(const ushort* __restrict__ featT,
                                                     const ushort* __restrict__ Bc,
                                                     const float* __restrict__ b_comp,
                                                     ushort* __restrict__ compB) {
    int p0 = blockIdx.x * 16;
    int tid = threadIdx.x, lane = tid & 63, nf = tid >> 6;
    int lr = lane & 15, lk = lane >> 4;
    f32x4 acc = {0, 0, 0, 0};
    const ushort* ap0 = featT + (size_t)(p0 + lr) * 256 + lk * 8;
    const ushort* bp0 = Bc + ((size_t)nf * 64 + lane) * 8;
    #pragma unroll
    for (int ks = 0; ks < 8; ++ks) {
        short8v a = *reinterpret_cast<const short8v*>(ap0 + ks * 32);
        short8v b = *reinterpret_cast<const short8v*>(bp0 + (size_t)ks * 2048);
        acc = __builtin_amdgcn_mfma_f32_16x16x32_bf16(a, b, acc, 0, 0, 0);
    }
    int cc = nf * 16 + lr;
    float bv = b_comp[cc];
    #pragma unroll
    for (int i = 0; i < 4; ++i) {
        int p = p0 + lk * 4 + i;
        compB[(size_t)p * 64 + cc] = f2bf(acc[i] + bv);
    }
}

// enc conv as MFMA GEMM (M=16/block, N=128 pad, K=576) + fused 25-tap softmax.
// 512 blocks x 8 waves; wave = one N-fragment. 4 waves/SIMD at 2 blocks/CU.
__global__ __launch_bounds__(512) void enc_gemm_softmax(const ushort* __restrict__ compB,
                                                        const ushort* __restrict__ Bsw,
                                                        float* __restrict__ wgt) {
    int p0 = blockIdx.x * 16;
    int n = p0 >> 12, h = (p0 >> 6) & 63, w0 = p0 & 63;
    int tid = threadIdx.x, lane = tid & 63, nf = tid >> 6;
    int lr = lane & 15, lk = lane >> 4;
    int wpix = w0 + lr;
    f32x4 acc = {0, 0, 0, 0};
    #pragma unroll
    for (int ks = 0; ks < 18; ++ks) {
        int ct = ks >> 1, dh = ct / 3, dw = ct - dh * 3;
        int hh = h + dh - 1;
        if ((unsigned)hh >= 64u) continue;     // block-uniform
        int ww = wpix + dw - 1;
        short8v a = {};
        if ((unsigned)ww < 64u)
            a = *reinterpret_cast<const short8v*>(
                    compB + ((size_t)(n * 4096 + hh * 64 + ww) * 64 + (ks & 1) * 32 + lk * 8));
        short8v b = *reinterpret_cast<const short8v*>(
                    Bsw + ((size_t)(ks * 8 + nf) * 64 + lane) * 8);
        acc = __builtin_amdgcn_mfma_f32_16x16x32_bf16(a, b, acc, 0, 0, 0);
    }
    __shared__ float kp_lds[16][132];
    #pragma unroll
    for (int i = 0; i < 4; ++i)
        kp_lds[lk * 4 + i][nf * 16 + lr] = acc[i];
    __syncthreads();
    if (tid < 64) {
        int pl = tid & 15, sub = tid >> 4;
        float v[25], mx = -1e30f;
        #pragma unroll
        for (int t = 0; t < 25; ++t) { v[t] = kp_lds[pl][t * 4 + sub]; mx = fmaxf(mx, v[t]); }
        float s = 0.f;
        #pragma unroll
        for (int t = 0; t < 25; ++t) { v[t] = expf(v[t] - mx); s += v[t]; }
        float inv = 1.f / s;
        float* o = wgt + ((size_t)((n * 64 + h) * 4 + sub)) * 1600 + (w0 + pl);
        #pragma unroll
        for (int t = 0; t < 25; ++t) o[t * 64] = v[t] * inv;
    }
}

// apply: out[n][c][2h+dy][2w+dx] = sum_{i,j} feat[n][c][h+i-2][w+j-2] * wgt[n][h][dy*2+dx][i*5+j][w]
__global__ __launch_bounds__(256) void apply_kernel(const float* __restrict__ feat,
                                                    const float* __restrict__ wgt,
                                                    float* __restrict__ out) {
    int b = blockIdx.x;
    int cg = b & 7;
    int h  = (b >> 3) & 63;
    int n  = b >> 9;
    int tid = threadIdx.x;
    int w  = tid & 63;
    int ci = tid >> 6;
    int c0 = cg * 32 + ci * 8;
    const float* fbase = feat + ((size_t)(n * CIN + c0)) * 4096;
    const float* wg = wgt + ((size_t)((n * 64 + h) * 4)) * 1600; // [sub][25][64]

    float acc[4][8];
    #pragma unroll
    for (int s = 0; s < 4; ++s)
        #pragma unroll
        for (int k = 0; k < 8; ++k) acc[s][k] = 0.f;

    #pragma unroll
    for (int i = 0; i < 5; ++i) {
        int hh = h + i - 2;
        if ((unsigned)hh >= 64u) continue;        // block-uniform branch
        #pragma unroll
        for (int j = 0; j < 5; ++j) {
            int ww = w + j - 2;
            bool ok = (unsigned)ww < 64u;
            int t = i * 5 + j;
            float wv[4];
            #pragma unroll
            for (int s = 0; s < 4; ++s) wv[s] = wg[(s * 25 + t) * 64 + w];
            #pragma unroll
            for (int k = 0; k < 8; ++k) {
                float fv = ok ? fbase[(size_t)k * 4096 + (hh << 6) + ww] : 0.f;
                #pragma unroll
                for (int s = 0; s < 4; ++s) acc[s][k] += fv * wv[s];
            }
        }
    }

    #pragma unroll
    for (int k = 0; k < 8; ++k) {
        float* o = out + ((size_t)(n * CIN + c0 + k) * 128 + 2 * h) * 128 + 2 * w;
        *reinterpret_cast<float2*>(o) = make_float2(acc[0][k], acc[1][k]);
        *reinterpret_cast<float2*>(o + 128) = make_float2(acc[2][k], acc[3][k]);
    }
}

extern "C" void kernel_launch(void* const* d_in, const int* in_sizes, int n_in,
                              void* d_out, int out_size, void* d_ws, size_t ws_size,
                              hipStream_t stream) {
    const float* features = (const float*)d_in[0];
    const float* w_comp   = (const float*)d_in[1];
    const float* b_comp   = (const float*)d_in[2];
    const float* w_enc    = (const float*)d_in[3];
    float* out = (float*)d_out;
    float* ws  = (float*)d_ws;

    ushort* Bsw   = (ushort*)ws;                 // 73728 bf16
    ushort* Bc    = (ushort*)(ws + 36864);       // 16384 bf16
    ushort* featT = (ushort*)(ws + 45056);       // 2097152 bf16
    float*  wgt   = ws + 45056;                  // aliases featT (featT dead after compress_gemm)
    ushort* compB = (ushort*)(ws + 1093632);     // 524288 bf16

    hipLaunchKernelGGL(prep_weights,     dim3(352), dim3(256), 0, stream, w_comp, w_enc, Bsw, Bc);
    hipLaunchKernelGGL(feat_transpose,   dim3(512), dim3(256), 0, stream, features, featT);
    hipLaunchKernelGGL(compress_gemm,    dim3(512), dim3(256), 0, stream, featT, Bc, b_comp, compB);
    hipLaunchKernelGGL(enc_gemm_softmax, dim3(512), dim3(512), 0, stream, compB, Bsw, wgt);
    hipLaunchKernelGGL(apply_kernel,     dim3(1024), dim3(256), 0, stream, features, wgt, out);
}

// Round 4
// 44.503 us; speedup vs baseline: 2.6133x; 1.2617x over previous
//
#include <hip/hip_runtime.h>
#include <hip/hip_bf16.h>
#include <math.h>

// CARAFE on MI355X (gfx950).
// features: (2,256,64,64) f32 ; w_comp: (64,256) ; b_comp: (64,) ; w_enc: (100,64,3,3)
// out: (2,256,128,128) f32
#define CIN 256

typedef __attribute__((ext_vector_type(8))) short short8v;  // 8 bf16 (4 VGPRs)
typedef __attribute__((ext_vector_type(4))) float f32x4;    // MFMA accum

// ws layout (float units):
//  Bsw   [18ks][8nf][64lane][8] bf16   @ 0         (36864 fl)
//  Bc    [8ks][4nf][64lane][8] bf16    @ 36864     (8192 fl)
//  featT [8192 p][256 c] bf16          @ 45056     (1048576 fl)
//  wgt   [2][64h][4sub][25tap][64w] f32 @ 45056    (819200 fl)  -- ALIASES featT (dead by then)
//  compB [8192 p][64 cc] bf16          @ 1093632   (262144 fl)

__device__ inline ushort f2bf(float x) {
    __hip_bfloat16 b = __float2bfloat16(x);
    return *reinterpret_cast<ushort*>(&b);
}

// Fused weight prep (enc B-frags, compress B-frags) + feat NCHW->[p][c] bf16 transpose.
__global__ __launch_bounds__(256) void prep_all(const float* __restrict__ w_comp,
                                                const float* __restrict__ w_enc,
                                                const float* __restrict__ feat,
                                                ushort* __restrict__ Bsw,
                                                ushort* __restrict__ Bc,
                                                ushort* __restrict__ featT) {
    __shared__ float lds[64][65];
    int bid = blockIdx.x, tid = threadIdx.x;
    if (bid < 288) {
        // enc GEMM B: k = convtap*64 + cc (K=576, 18 ksteps), o = outtap*4+sub (N pad 128)
        int i = bid * 256 + tid;                 // 73728
        int j = i & 7, lane = (i >> 3) & 63, rest = i >> 9;
        int nf = rest & 7, ks = rest >> 3;       // ks 0..17
        int ct = ks >> 1, dh = ct / 3, dw = ct % 3;
        int cc = (ks & 1) * 32 + (lane >> 4) * 8 + j;
        int o  = nf * 16 + (lane & 15);
        float v = (o < 100) ? w_enc[((o * 64 + cc) * 3 + dh) * 3 + dw] : 0.f;
        Bsw[i] = f2bf(v);
    } else if (bid < 352) {
        // compress GEMM B: k = c (K=256, 8 ksteps), col = cc (N=64)
        int i = (bid - 288) * 256 + tid;         // 16384
        int j = i & 7, lane = (i >> 3) & 63, rest = i >> 9;
        int nf = rest & 3, ks = rest >> 2;       // ks 0..7
        int c  = ks * 32 + (lane >> 4) * 8 + j;
        int cc = nf * 16 + (lane & 15);
        Bc[i] = f2bf(w_comp[cc * 256 + c]);
    } else {
        // feat transpose via 64x64 LDS tile
        int b = bid - 352;                       // 512 = 128 p-tiles x 4 c-tiles
        int ct = b & 3, pt = b >> 2;
        int c0 = ct * 64, p0 = pt * 64;
        int n = p0 >> 12, hw0 = p0 & 4095;
        int pl = tid & 63, cr = tid >> 6;
        const float* src = feat + ((size_t)(n * CIN + c0 + cr)) * 4096 + hw0 + pl;
        #pragma unroll
        for (int rr = 0; rr < 16; ++rr)
            lds[rr * 4 + cr][pl] = src[(size_t)rr * 4 * 4096];
        __syncthreads();
        int cp = tid & 31, pr = tid >> 5;
        uint* dst = (uint*)featT;
        #pragma unroll
        for (int rr = 0; rr < 8; ++rr) {
            int pp = rr * 8 + pr;
            uint u = (uint)f2bf(lds[cp * 2][pp]) | ((uint)f2bf(lds[cp * 2 + 1][pp]) << 16);
            dst[(((size_t)(p0 + pp) * 256 + c0) >> 1) + cp] = u;
        }
    }
}

// compress as MFMA GEMM: comp[p][cc] = bias[cc] + sum_c featT[p][c] * w_comp[cc][c]
__global__ __launch_bounds__(256) void compress_gemm(const ushort* __restrict__ featT,
                                                     const ushort* __restrict__ Bc,
                                                     const float* __restrict__ b_comp,
                                                     ushort* __restrict__ compB) {
    int p0 = blockIdx.x * 16;
    int tid = threadIdx.x, lane = tid & 63, nf = tid >> 6;
    int lr = lane & 15, lk = lane >> 4;
    f32x4 acc = {0, 0, 0, 0};
    const ushort* ap0 = featT + (size_t)(p0 + lr) * 256 + lk * 8;
    const ushort* bp0 = Bc + ((size_t)nf * 64 + lane) * 8;
    #pragma unroll
    for (int ks = 0; ks < 8; ++ks) {
        short8v a = *reinterpret_cast<const short8v*>(ap0 + ks * 32);
        short8v b = *reinterpret_cast<const short8v*>(bp0 + (size_t)ks * 2048);
        acc = __builtin_amdgcn_mfma_f32_16x16x32_bf16(a, b, acc, 0, 0, 0);
    }
    int cc = nf * 16 + lr;
    float bv = b_comp[cc];
    #pragma unroll
    for (int i = 0; i < 4; ++i) {
        int p = p0 + lk * 4 + i;
        compB[(size_t)p * 64 + cc] = f2bf(acc[i] + bv);
    }
}

// enc conv as MFMA GEMM (M=16/block, N=128 pad, K=576) + fused 25-tap softmax.
__global__ __launch_bounds__(512) void enc_gemm_softmax(const ushort* __restrict__ compB,
                                                        const ushort* __restrict__ Bsw,
                                                        float* __restrict__ wgt) {
    int p0 = blockIdx.x * 16;
    int n = p0 >> 12, h = (p0 >> 6) & 63, w0 = p0 & 63;
    int tid = threadIdx.x, lane = tid & 63, nf = tid >> 6;
    int lr = lane & 15, lk = lane >> 4;
    int wpix = w0 + lr;
    f32x4 acc = {0, 0, 0, 0};
    #pragma unroll
    for (int ks = 0; ks < 18; ++ks) {
        int ct = ks >> 1, dh = ct / 3, dw = ct - dh * 3;
        int hh = h + dh - 1;
        if ((unsigned)hh >= 64u) continue;     // block-uniform
        int ww = wpix + dw - 1;
        short8v a = {};
        if ((unsigned)ww < 64u)
            a = *reinterpret_cast<const short8v*>(
                    compB + ((size_t)(n * 4096 + hh * 64 + ww) * 64 + (ks & 1) * 32 + lk * 8));
        short8v b = *reinterpret_cast<const short8v*>(
                    Bsw + ((size_t)(ks * 8 + nf) * 64 + lane) * 8);
        acc = __builtin_amdgcn_mfma_f32_16x16x32_bf16(a, b, acc, 0, 0, 0);
    }
    __shared__ float kp_lds[16][132];
    #pragma unroll
    for (int i = 0; i < 4; ++i)
        kp_lds[lk * 4 + i][nf * 16 + lr] = acc[i];
    __syncthreads();
    if (tid < 64) {
        int pl = tid & 15, sub = tid >> 4;
        float v[25], mx = -1e30f;
        #pragma unroll
        for (int t = 0; t < 25; ++t) { v[t] = kp_lds[pl][t * 4 + sub]; mx = fmaxf(mx, v[t]); }
        float s = 0.f;
        #pragma unroll
        for (int t = 0; t < 25; ++t) { v[t] = expf(v[t] - mx); s += v[t]; }
        float inv = 1.f / s;
        float* o = wgt + ((size_t)((n * 64 + h) * 4 + sub)) * 1600 + (w0 + pl);
        #pragma unroll
        for (int t = 0; t < 25; ++t) o[t * 64] = v[t] * inv;
    }
}

// apply v2: out[n][c][2h+dy][2w+dx] = sum_{i,j} feat[n][c][h+i-2][w+j-2] * wgt[n][h][dy*2+dx][i*5+j][w]
// Block = (n,h, cg of 32 ch); 1024 blocks, 256 thr (64 w x 4 ci), thread = 8 ch x 4 sub.
// feat loaded once per (ch,row); w-neighbors via __shfl. wgt staged in LDS.
// XCD swizzle: 128 consecutive wgid per XCD -> wgt row (8 blocks) + h-adjacent feat on one XCD.
__global__ __launch_bounds__(256, 4) void apply_v2(const float* __restrict__ feat,
                                                   const float* __restrict__ wgt,
                                                   float* __restrict__ out) {
    int bid = blockIdx.x;
    int wgid = (bid & 7) * 128 + (bid >> 3);   // bijective: 1024 % 8 == 0
    int cg = wgid & 7;                         // 8 groups of 32 ch
    int nh = wgid >> 3;                        // n*64+h
    int n = nh >> 6, h = nh & 63;
    int tid = threadIdx.x;
    int w  = tid & 63;
    int ci = tid >> 6;
    int c0 = cg * 32 + ci * 8;

    __shared__ float wlds[4 * 25 * 64];        // 25.6 KB: [sub][tap][w]
    {
        const float* wg = wgt + (size_t)nh * 6400;
        #pragma unroll
        for (int it = 0; it < 25; ++it)
            wlds[it * 256 + tid] = wg[it * 256 + tid];
    }
    __syncthreads();

    const float* fbase = feat + ((size_t)(n * CIN + c0)) * 4096;

    float acc[4][8];
    #pragma unroll
    for (int s = 0; s < 4; ++s)
        #pragma unroll
        for (int k = 0; k < 8; ++k) acc[s][k] = 0.f;

    #pragma unroll
    for (int i = 0; i < 5; ++i) {
        int hh = h + i - 2;
        if ((unsigned)hh >= 64u) continue;     // block-uniform: zero-pad rows contribute 0
        // 20 weights for this i
        float wv[4][5];
        #pragma unroll
        for (int s = 0; s < 4; ++s)
            #pragma unroll
            for (int j = 0; j < 5; ++j)
                wv[s][j] = wlds[(s * 25 + i * 5 + j) * 64 + w];
        #pragma unroll
        for (int k = 0; k < 8; ++k) {
            float v = fbase[(size_t)k * 4096 + (hh << 6) + w];   // one coalesced load
            #pragma unroll
            for (int j = 0; j < 5; ++j) {
                int col = w + j - 2;
                float fv = __shfl(v, col, 64);
                fv = ((unsigned)col < 64u) ? fv : 0.f;
                #pragma unroll
                for (int s = 0; s < 4; ++s) acc[s][k] += fv * wv[s][j];
            }
        }
    }

    #pragma unroll
    for (int k = 0; k < 8; ++k) {
        float* o = out + ((size_t)(n * CIN + c0 + k) * 128 + 2 * h) * 128 + 2 * w;
        *reinterpret_cast<float2*>(o) = make_float2(acc[0][k], acc[1][k]);
        *reinterpret_cast<float2*>(o + 128) = make_float2(acc[2][k], acc[3][k]);
    }
}

extern "C" void kernel_launch(void* const* d_in, const int* in_sizes, int n_in,
                              void* d_out, int out_size, void* d_ws, size_t ws_size,
                              hipStream_t stream) {
    const float* features = (const float*)d_in[0];
    const float* w_comp   = (const float*)d_in[1];
    const float* b_comp   = (const float*)d_in[2];
    const float* w_enc    = (const float*)d_in[3];
    float* out = (float*)d_out;
    float* ws  = (float*)d_ws;

    ushort* Bsw   = (ushort*)ws;                 // 73728 bf16
    ushort* Bc    = (ushort*)(ws + 36864);       // 16384 bf16
    ushort* featT = (ushort*)(ws + 45056);       // 2097152 bf16
    float*  wgt   = ws + 45056;                  // aliases featT (dead after compress_gemm)
    ushort* compB = (ushort*)(ws + 1093632);     // 524288 bf16

    hipLaunchKernelGGL(prep_all,         dim3(864), dim3(256), 0, stream,
                       w_comp, w_enc, features, Bsw, Bc, featT);
    hipLaunchKernelGGL(compress_gemm,    dim3(512), dim3(256), 0, stream, featT, Bc, b_comp, compB);
    hipLaunchKernelGGL(enc_gemm_softmax, dim3(512), dim3(512), 0, stream, compB, Bsw, wgt);
    hipLaunchKernelGGL(apply_v2,         dim3(1024), dim3(256), 0, stream, features, wgt, out);
}